// Round 7
// baseline (14912.347 us; speedup 1.0000x reference)
//
#include <hip/hip_runtime.h>
#include <math.h>

// ---------------------------------------------------------------------------
// Hierarchical bi-GRU (char bi-GRU -> word bi-GRU -> FC head), fp32.
//
//   gates = sigmoid(x@Wg_x + h@Wg_h + bg)      (x-part precomputed)
//   c     = tanh  (x@Wc_x + (r*h)@Wc_h + bc)
//   h'    = mask ? u*h + (1-u)*c : h
//
// Fused persistent GRU v3: 512 threads, block owns R rows (char R=16 -> 1
// block/CU w/ 98KB dynamic LDS; word R=4). Two row-halves: threads 0-255 do
// rows [0,R/2), 256-511 do [R/2,R); each thread owns a float4 col-slice in
// phase 1 and a float2 slice in phase 2. Weights stream from L2 with an
// explicit 8-deep register prefetch. Higher R = fewer weight streams per
// step (per-XCD L2 traffic halved vs r5 char, quartered for word).
// ---------------------------------------------------------------------------

#define TILE 64
#define BKK 16

enum AMode { A_PLAIN = 0, A_CHARSTATE = 1, A_GATHER = 3 };
enum EMode { E_BIAS = 0, E_XW = 3 };

struct GemmArgs {
  int M, N, K;
  const float* A; int lda;
  const int*   arows;
  const float* B;
  const float* bias;
  const float* XT; int ldxt;
  const int*   cidx;
  float* Cout; int ldc;
};

__device__ __forceinline__ float sigmoidf_(float x) { return 1.0f / (1.0f + expf(-x)); }
__device__ __forceinline__ void fma4_(float4& a, float s, const float4& w) {
  a.x += s * w.x; a.y += s * w.y; a.z += s * w.z; a.w += s * w.w;
}
__device__ __forceinline__ void fma2_(float2& a, float s, const float2& w) {
  a.x += s * w.x; a.y += s * w.y;
}

template<int AM, int EM>
__global__ __launch_bounds__(256) void gemm_k(GemmArgs p) {
  __shared__ float As[BKK][TILE];
  __shared__ float Bs[BKK][TILE];
  const int tid = threadIdx.x;
  const int tx = tid & 15, ty = tid >> 4;
  const int m0 = blockIdx.y * TILE, n0 = blockIdx.x * TILE;
  const int la_r = tid >> 2, la_k = (tid & 3) << 2;
  const int lb_k = tid >> 4, lb_n = (tid & 15) << 2;

  float acc[4][4] = {};
  int arow = 0;
  if constexpr (AM == A_GATHER) arow = p.arows[m0 + la_r];

  for (int k0 = 0; k0 < p.K; k0 += BKK) {
    float4 av;
    const int m = m0 + la_r;
    const int k = k0 + la_k;
    if constexpr (AM == A_PLAIN) {
      av = *reinterpret_cast<const float4*>(p.A + (size_t)m * p.lda + k);
    } else if constexpr (AM == A_CHARSTATE) {
      const float* ap = (k < 512) ? (p.A + (size_t)m * 512 + k)
                                  : (p.A + (size_t)(2048 + m) * 512 + (k - 512));
      av = *reinterpret_cast<const float4*>(ap);
    } else { // A_GATHER
      av = *reinterpret_cast<const float4*>(p.A + (size_t)arow * p.lda + k);
    }
    As[la_k + 0][la_r] = av.x;
    As[la_k + 1][la_r] = av.y;
    As[la_k + 2][la_r] = av.z;
    As[la_k + 3][la_r] = av.w;
    float4 bv = *reinterpret_cast<const float4*>(p.B + (size_t)(k0 + lb_k) * p.N + n0 + lb_n);
    *reinterpret_cast<float4*>(&Bs[lb_k][lb_n]) = bv;
    __syncthreads();
#pragma unroll
    for (int kk = 0; kk < BKK; ++kk) {
      float4 a = *reinterpret_cast<const float4*>(&As[kk][ty << 2]);
      float4 b = *reinterpret_cast<const float4*>(&Bs[kk][tx << 2]);
      acc[0][0] += a.x * b.x; acc[0][1] += a.x * b.y; acc[0][2] += a.x * b.z; acc[0][3] += a.x * b.w;
      acc[1][0] += a.y * b.x; acc[1][1] += a.y * b.y; acc[1][2] += a.y * b.z; acc[1][3] += a.y * b.w;
      acc[2][0] += a.z * b.x; acc[2][1] += a.z * b.y; acc[2][2] += a.z * b.z; acc[2][3] += a.z * b.w;
      acc[3][0] += a.w * b.x; acc[3][1] += a.w * b.y; acc[3][2] += a.w * b.z; acc[3][3] += a.w * b.w;
    }
    __syncthreads();
  }

  const int rbase = m0 + (ty << 2);
  const int cbase = n0 + (tx << 2);
#pragma unroll
  for (int i = 0; i < 4; ++i) {
    const int row = rbase + i;
    if constexpr (EM == E_BIAS) {
#pragma unroll
      for (int j = 0; j < 4; ++j) {
        const int col = cbase + j;
        p.Cout[(size_t)row * p.ldc + col] = acc[i][j] + p.bias[col];
      }
    } else { // E_XW
      const int cs = p.cidx[row];
      const float* xrow = p.XT + (size_t)cs * p.ldxt;
#pragma unroll
      for (int j = 0; j < 4; ++j) {
        const int col = cbase + j;
        p.Cout[(size_t)row * p.ldc + col] = acc[i][j] + xrow[col];
      }
    }
  }
}

// ---------------------------------------------------------------------------
// Fused persistent GRU v3 (see header comment).
// Dynamic LDS layout: h[R][512] | rh[R][512] | u[R][512].
// ---------------------------------------------------------------------------
template<int R, int NU, int TT, bool CHARMODE>
__global__ __launch_bounds__(512, 1) void gru_fused(
    const float* __restrict__ Whg,   // [512,1024] h-part gate weights
    const float* __restrict__ Whc,   // [512,512]  h-part cand weights
    const float* __restrict__ Xg,    // gate x-part table (bias folded)
    const float* __restrict__ Xc,    // cand x-part table
    const int*   __restrict__ lens,  // [NU]
    const int*   __restrict__ seqs,  // CHARMODE: [NU,TT]
    float* __restrict__ Hout)        // [2*NU, 512]
{
  constexpr int HR = R / 2;
  extern __shared__ float lds[];
  float* h_s  = lds;                 // [R*512]
  float* rh_s = lds + R * 512;       // [R*512]
  float* u_s  = lds + 2 * R * 512;   // [R*512]
  __shared__ int seq_s[CHARMODE ? R * TT : 1];
  __shared__ int xog_s[R];
  __shared__ int xoc_s[R];
  __shared__ int msk_s[R];
  __shared__ int len_s[R];
  __shared__ int maxlen_s;

  const int tid = threadIdx.x;
  const int G   = NU / R;
  const bool bw = blockIdx.x >= G;
  const int g   = bw ? (blockIdx.x - G) : blockIdx.x;
  const int us0 = g * R;

  if (tid < R) len_s[tid] = lens[us0 + tid];
  for (int i = tid; i < R * 512; i += 512) h_s[i] = 0.0f;
  if constexpr (CHARMODE) {
    for (int i = tid; i < R * TT; i += 512)
      seq_s[i] = seqs[(size_t)(us0 + i / TT) * TT + (i % TT)];
  }
  __syncthreads();
  if (tid == 0) {
    int m = 0;
#pragma unroll
    for (int r = 0; r < R; ++r) m = len_s[r] > m ? len_s[r] : m;
    maxlen_s = m;
  }
  __syncthreads();

  const int hh   = tid >> 8;        // row half 0/1
  const int lt   = tid & 255;
  const int c4   = lt << 2;         // phase-1 col base (of 1024)
  const int c2   = lt << 1;         // phase-2 col base (of 512)
  const int row0 = hh * HR;

  for (int t = 0; t < TT; ++t) {
    if (t >= maxlen_s) break;

    if (tid < R) {
      const int L = len_s[tid];
      int pos = bw ? (L - 1 - t) : t;
      pos = pos < 0 ? 0 : (pos > TT - 1 ? TT - 1 : pos);
      int xr;
      if constexpr (CHARMODE) xr = seq_s[tid * TT + pos];
      else                    xr = (us0 + tid) * TT + pos;
      xog_s[tid] = xr << 10;
      xoc_s[tid] = xr << 9;
      msk_s[tid] = (t < L) ? 1 : 0;
    }
    __syncthreads();

    // ---- phase 1: gates = sigmoid(h @ Whg + Xg); rh, u -> LDS ----
    float4 acc1[HR];
#pragma unroll
    for (int r = 0; r < HR; ++r) acc1[r] = make_float4(0.f, 0.f, 0.f, 0.f);
    {
      const float* wg = Whg + c4;
      float4 wc[8], wn[8];
#pragma unroll
      for (int i = 0; i < 8; ++i) wc[i] = *reinterpret_cast<const float4*>(wg + (size_t)i * 1024);
#pragma unroll 1
      for (int k0 = 0; k0 < 512; k0 += 8) {
        if (k0 + 8 < 512) {
#pragma unroll
          for (int i = 0; i < 8; ++i)
            wn[i] = *reinterpret_cast<const float4*>(wg + (size_t)(k0 + 8 + i) * 1024);
        }
#pragma unroll
        for (int r = 0; r < HR; ++r) {
          const float* hp = h_s + (row0 + r) * 512 + k0;
          const float4 h0 = *reinterpret_cast<const float4*>(hp);
          const float4 h1 = *reinterpret_cast<const float4*>(hp + 4);
          fma4_(acc1[r], h0.x, wc[0]); fma4_(acc1[r], h0.y, wc[1]);
          fma4_(acc1[r], h0.z, wc[2]); fma4_(acc1[r], h0.w, wc[3]);
          fma4_(acc1[r], h1.x, wc[4]); fma4_(acc1[r], h1.y, wc[5]);
          fma4_(acc1[r], h1.z, wc[6]); fma4_(acc1[r], h1.w, wc[7]);
        }
#pragma unroll
        for (int i = 0; i < 8; ++i) wc[i] = wn[i];
      }
    }
#pragma unroll
    for (int r = 0; r < HR; ++r) {
      const int row = row0 + r;
      const float4 xv = *reinterpret_cast<const float4*>(Xg + xog_s[row] + c4);
      float4 gv;
      gv.x = sigmoidf_(acc1[r].x + xv.x);
      gv.y = sigmoidf_(acc1[r].y + xv.y);
      gv.z = sigmoidf_(acc1[r].z + xv.z);
      gv.w = sigmoidf_(acc1[r].w + xv.w);
      if (c4 < 512) {   // r-gate -> rh = r*h
        const float4 hv = *reinterpret_cast<const float4*>(h_s + row * 512 + c4);
        float4 rv;
        rv.x = gv.x * hv.x; rv.y = gv.y * hv.y; rv.z = gv.z * hv.z; rv.w = gv.w * hv.w;
        *reinterpret_cast<float4*>(rh_s + row * 512 + c4) = rv;
      } else {          // u-gate
        *reinterpret_cast<float4*>(u_s + row * 512 + (c4 - 512)) = gv;
      }
    }
    __syncthreads();

    // ---- phase 2: c = tanh(rh @ Whc + Xc); h' = mask ? u*h+(1-u)*c : h ----
    float2 acc2[HR];
#pragma unroll
    for (int r = 0; r < HR; ++r) acc2[r] = make_float2(0.f, 0.f);
    {
      const float* wcb = Whc + c2;
      float2 vc[8], vn[8];
#pragma unroll
      for (int i = 0; i < 8; ++i) vc[i] = *reinterpret_cast<const float2*>(wcb + (size_t)i * 512);
#pragma unroll 1
      for (int k0 = 0; k0 < 512; k0 += 8) {
        if (k0 + 8 < 512) {
#pragma unroll
          for (int i = 0; i < 8; ++i)
            vn[i] = *reinterpret_cast<const float2*>(wcb + (size_t)(k0 + 8 + i) * 512);
        }
#pragma unroll
        for (int r = 0; r < HR; ++r) {
          const float* rp = rh_s + (row0 + r) * 512 + k0;
          const float4 r0 = *reinterpret_cast<const float4*>(rp);
          const float4 r1 = *reinterpret_cast<const float4*>(rp + 4);
          fma2_(acc2[r], r0.x, vc[0]); fma2_(acc2[r], r0.y, vc[1]);
          fma2_(acc2[r], r0.z, vc[2]); fma2_(acc2[r], r0.w, vc[3]);
          fma2_(acc2[r], r1.x, vc[4]); fma2_(acc2[r], r1.y, vc[5]);
          fma2_(acc2[r], r1.z, vc[6]); fma2_(acc2[r], r1.w, vc[7]);
        }
#pragma unroll
        for (int i = 0; i < 8; ++i) vc[i] = vn[i];
      }
    }
#pragma unroll
    for (int r = 0; r < HR; ++r) {
      const int row = row0 + r;
      const float2 xv = *reinterpret_cast<const float2*>(Xc + xoc_s[row] + c2);
      const float cx = tanhf(acc2[r].x + xv.x);
      const float cy = tanhf(acc2[r].y + xv.y);
      if (msk_s[row]) {
        const float ux = u_s[row * 512 + c2], uy = u_s[row * 512 + c2 + 1];
        const float hx = h_s[row * 512 + c2], hy = h_s[row * 512 + c2 + 1];
        h_s[row * 512 + c2]     = ux * hx + (1.0f - ux) * cx;
        h_s[row * 512 + c2 + 1] = uy * hy + (1.0f - uy) * cy;
      }
    }
    __syncthreads();
  }

  for (int i = tid; i < R * 512; i += 512)
    Hout[(size_t)(us0 + (i >> 9) + (bw ? NU : 0)) * 512 + (i & 511)] = h_s[i];
}

// FC head
__global__ __launch_bounds__(64) void head_k(const float* __restrict__ Hw,
                                             const float* __restrict__ W1,
                                             const float* __restrict__ b1,
                                             const float* __restrict__ W2,
                                             const float* __restrict__ b2,
                                             float* __restrict__ out) {
  __shared__ float s[1024];
  __shared__ float hid[64];
  const int b = blockIdx.x;
  const int tid = threadIdx.x;
  for (int k = tid; k < 512; k += 64) {
    s[k]       = Hw[(size_t)b * 512 + k];
    s[512 + k] = Hw[(size_t)(256 + b) * 512 + k];
  }
  __syncthreads();
  float acc = b1[tid];
  for (int k = 0; k < 1024; ++k) acc += s[k] * W1[k * 64 + tid];
  acc = acc > 0.0f ? acc : 0.2f * acc;
  hid[tid] = acc;
  __syncthreads();
  if (tid < 2) {
    float a = b2[tid];
    for (int k = 0; k < 64; ++k) a += hid[k] * W2[k * 2 + tid];
    out[b * 2 + tid] = a;
  }
}

extern "C" void kernel_launch(void* const* d_in, const int* in_sizes, int n_in,
                              void* d_out, int out_size, void* d_ws, size_t ws_size,
                              hipStream_t stream) {
  const int*   charseqs      = (const int*)d_in[0];
  const int*   charseq_lens  = (const int*)d_in[1];
  const int*   charseq_ids   = (const int*)d_in[2];
  const int*   word_ids      = (const int*)d_in[3];
  const int*   sentence_lens = (const int*)d_in[4];
  const float* char_emb      = (const float*)d_in[5];
  const float* word_emb      = (const float*)d_in[6];
  const float* Wg_c          = (const float*)d_in[7];
  const float* bg_c          = (const float*)d_in[8];
  const float* Wc_c          = (const float*)d_in[9];
  const float* bc_c          = (const float*)d_in[10];
  const float* Wg_w          = (const float*)d_in[11];
  const float* bg_w          = (const float*)d_in[12];
  const float* Wc_w          = (const float*)d_in[13];
  const float* bc_w          = (const float*)d_in[14];
  const float* W1            = (const float*)d_in[15];
  const float* b1            = (const float*)d_in[16];
  const float* W2            = (const float*)d_in[17];
  const float* b2            = (const float*)d_in[18];
  float* out = (float*)d_out;

  float* ws = (float*)d_ws;
  size_t off = 0;
  auto alloc = [&](size_t n) { float* p = ws + off; off += n; return p; };
  float* XTABg = alloc(256 * 1024);
  float* XTABc = alloc(256 * 512);
  float* Hc    = alloc((size_t)4096 * 512);
  float* CTABg = alloc((size_t)2048 * 1024);
  float* CTABc = alloc((size_t)2048 * 512);
  float* XWg   = alloc((size_t)16384 * 1024);
  float* XWc   = alloc((size_t)16384 * 512);
  float* Hw    = alloc(512 * 512);

  // --- Stage A: char x-part tables  [256,128]@[128,1536] ---
  {
    GemmArgs a{}; a.M = 256; a.N = 1024; a.K = 128;
    a.A = char_emb; a.lda = 128; a.B = Wg_c; a.bias = bg_c; a.Cout = XTABg; a.ldc = 1024;
    gemm_k<A_PLAIN, E_BIAS><<<dim3(1024 / TILE, 256 / TILE), 256, 0, stream>>>(a);
    GemmArgs c{}; c.M = 256; c.N = 512; c.K = 128;
    c.A = char_emb; c.lda = 128; c.B = Wc_c; c.bias = bc_c; c.Cout = XTABc; c.ldc = 512;
    gemm_k<A_PLAIN, E_BIAS><<<dim3(512 / TILE, 256 / TILE), 256, 0, stream>>>(c);
  }

  // --- Stage B: fused char bi-GRU (R=16 -> 256 blocks, 1/CU, 96KB dyn LDS) ---
  gru_fused<16, 2048, 16, true>
      <<<256, 512, 3 * 16 * 512 * sizeof(float), stream>>>(
      Wg_c + 128 * 1024, Wc_c + 128 * 512, XTABg, XTABc,
      charseq_lens, charseqs, Hc);

  // --- Stage C: per-wordform x-part of word GRU  [2048,1024]@[1024,1536] ---
  {
    GemmArgs a{}; a.M = 2048; a.N = 1024; a.K = 1024;
    a.A = Hc; a.B = Wg_w; a.bias = bg_w; a.Cout = CTABg; a.ldc = 1024;
    gemm_k<A_CHARSTATE, E_BIAS><<<dim3(1024 / TILE, 2048 / TILE), 256, 0, stream>>>(a);
    GemmArgs c{}; c.M = 2048; c.N = 512; c.K = 1024;
    c.A = Hc; c.B = Wc_w; c.bias = bc_w; c.Cout = CTABc; c.ldc = 512;
    gemm_k<A_CHARSTATE, E_BIAS><<<dim3(512 / TILE, 2048 / TILE), 256, 0, stream>>>(c);
  }

  // --- Stage D: word-emb x-part + CTAB gather  [16384,256]@[256,1536] ---
  {
    GemmArgs a{}; a.M = 16384; a.N = 1024; a.K = 256;
    a.A = word_emb; a.lda = 256; a.arows = word_ids; a.B = Wg_w + (size_t)1024 * 1024;
    a.XT = CTABg; a.ldxt = 1024; a.cidx = charseq_ids; a.Cout = XWg; a.ldc = 1024;
    gemm_k<A_GATHER, E_XW><<<dim3(1024 / TILE, 16384 / TILE), 256, 0, stream>>>(a);
    GemmArgs c{}; c.M = 16384; c.N = 512; c.K = 256;
    c.A = word_emb; c.lda = 256; c.arows = word_ids; c.B = Wc_w + (size_t)1024 * 512;
    c.XT = CTABc; c.ldxt = 512; c.cidx = charseq_ids; c.Cout = XWc; c.ldc = 512;
    gemm_k<A_GATHER, E_XW><<<dim3(512 / TILE, 16384 / TILE), 256, 0, stream>>>(c);
  }

  // --- Stage E: fused word bi-GRU (R=4 -> 128 blocks, 24KB dyn LDS) ---
  gru_fused<4, 256, 64, false>
      <<<128, 512, 3 * 4 * 512 * sizeof(float), stream>>>(
      Wg_w + (size_t)1280 * 1024, Wc_w + (size_t)1280 * 512, XWg, XWc,
      sentence_lens, nullptr, Hw);

  // --- Stage F: FC head ---
  head_k<<<256, 64, 0, stream>>>(Hw, W1, b1, W2, b2, out);
}

// Round 8
// 4853.319 us; speedup vs baseline: 3.0726x; 3.0726x over previous
//
#include <hip/hip_runtime.h>
#include <math.h>

// ---------------------------------------------------------------------------
// Hierarchical bi-GRU (char bi-GRU -> word bi-GRU -> FC head), fp32.
//
// HYBRID (r8): char level = unfused GEMM loop (64x64-tile gemm_k, 64-row
// weight reuse -> ~4x less L2 traffic than fused); word level = r5's fused
// persistent kernel (launch-latency-free, measured ~1.85ms, near L2 BW).
//
//   gates = sigmoid(x@Wg_x + h@Wg_h + bg)      (x-part precomputed)
//   c     = tanh  (x@Wc_x + (r*h)@Wc_h + bc)
//   h'    = mask ? u*h + (1-u)*c : h
// ---------------------------------------------------------------------------

#define TILE 64
#define BKK 16

enum AMode { A_PLAIN = 0, A_CHARSTATE = 1, A_RH = 2, A_GATHER = 3 };
enum EMode { E_BIAS = 0, E_GATE_CHAR = 1, E_CAND_CHAR = 2, E_XW = 3 };

struct GemmArgs {
  int M, N, K;
  const float* A; int lda;      // A_PLAIN/A_RH/A_GATHER base; A_CHARSTATE: Hc [4096,512]
  const float* G; int ldg;      // A_RH: r-gates; E_CAND_CHAR: u-gate source (cols 512..1023)
  const int*   arows;           // A_GATHER row indices
  const float* B;               // [K,N] row-major
  const float* bias;            // E_BIAS
  const float* XT; int ldxt;    // epilogue additive table (x-part)
  const int*   seqs;            // charseqs (E_*_CHAR)
  const int*   lens;            // sequence lengths
  int t, T;
  const int*   cidx;            // E_XW per-row table indices
  const float* Hin;             // E_CAND_CHAR: previous h (row stride 512)
  float* Cout; int ldc;
};

__device__ __forceinline__ float sigmoidf_(float x) { return 1.0f / (1.0f + expf(-x)); }

template<int AM, int EM>
__global__ __launch_bounds__(256) void gemm_k(GemmArgs p) {
  __shared__ float As[BKK][TILE];
  __shared__ float Bs[BKK][TILE];
  const int tid = threadIdx.x;
  const int tx = tid & 15, ty = tid >> 4;
  const int m0 = blockIdx.y * TILE, n0 = blockIdx.x * TILE;
  const int la_r = tid >> 2, la_k = (tid & 3) << 2;
  const int lb_k = tid >> 4, lb_n = (tid & 15) << 2;

  float acc[4][4] = {};
  int arow = 0;
  if constexpr (AM == A_GATHER) arow = p.arows[m0 + la_r];

  for (int k0 = 0; k0 < p.K; k0 += BKK) {
    float4 av;
    const int m = m0 + la_r;
    const int k = k0 + la_k;
    if constexpr (AM == A_PLAIN) {
      av = *reinterpret_cast<const float4*>(p.A + (size_t)m * p.lda + k);
    } else if constexpr (AM == A_CHARSTATE) {
      const float* ap = (k < 512) ? (p.A + (size_t)m * 512 + k)
                                  : (p.A + (size_t)(2048 + m) * 512 + (k - 512));
      av = *reinterpret_cast<const float4*>(ap);
    } else if constexpr (AM == A_RH) {
      float4 g = *reinterpret_cast<const float4*>(p.G + (size_t)m * p.ldg + k);
      float4 h = *reinterpret_cast<const float4*>(p.A + (size_t)m * p.lda + k);
      av = make_float4(g.x * h.x, g.y * h.y, g.z * h.z, g.w * h.w);
    } else { // A_GATHER
      av = *reinterpret_cast<const float4*>(p.A + (size_t)arow * p.lda + k);
    }
    As[la_k + 0][la_r] = av.x;
    As[la_k + 1][la_r] = av.y;
    As[la_k + 2][la_r] = av.z;
    As[la_k + 3][la_r] = av.w;
    float4 bv = *reinterpret_cast<const float4*>(p.B + (size_t)(k0 + lb_k) * p.N + n0 + lb_n);
    *reinterpret_cast<float4*>(&Bs[lb_k][lb_n]) = bv;
    __syncthreads();
#pragma unroll
    for (int kk = 0; kk < BKK; ++kk) {
      float4 a = *reinterpret_cast<const float4*>(&As[kk][ty << 2]);
      float4 b = *reinterpret_cast<const float4*>(&Bs[kk][tx << 2]);
      acc[0][0] += a.x * b.x; acc[0][1] += a.x * b.y; acc[0][2] += a.x * b.z; acc[0][3] += a.x * b.w;
      acc[1][0] += a.y * b.x; acc[1][1] += a.y * b.y; acc[1][2] += a.y * b.z; acc[1][3] += a.y * b.w;
      acc[2][0] += a.z * b.x; acc[2][1] += a.z * b.y; acc[2][2] += a.z * b.z; acc[2][3] += a.z * b.w;
      acc[3][0] += a.w * b.x; acc[3][1] += a.w * b.y; acc[3][2] += a.w * b.z; acc[3][3] += a.w * b.w;
    }
    __syncthreads();
  }

  const int rbase = m0 + (ty << 2);
  const int cbase = n0 + (tx << 2);
#pragma unroll
  for (int i = 0; i < 4; ++i) {
    const int row = rbase + i;
    if constexpr (EM == E_BIAS) {
#pragma unroll
      for (int j = 0; j < 4; ++j) {
        const int col = cbase + j;
        p.Cout[(size_t)row * p.ldc + col] = acc[i][j] + p.bias[col];
      }
    } else if constexpr (EM == E_GATE_CHAR || EM == E_CAND_CHAR) {
      const int us = row & 2047;
      const bool dir = row >= 2048;               // bw half of the batch
      const int len = p.lens[us];
      int pos = dir ? (len - 1 - p.t) : p.t;
      pos = pos < 0 ? 0 : (pos > p.T - 1 ? p.T - 1 : pos);
      const int ch = p.seqs[us * p.T + pos];
      const float* xrow = p.XT + (size_t)ch * p.ldxt;
      const bool mask = p.t < len;
#pragma unroll
      for (int j = 0; j < 4; ++j) {
        const int col = cbase + j;
        if constexpr (EM == E_GATE_CHAR) {
          p.Cout[(size_t)row * p.ldc + col] = sigmoidf_(acc[i][j] + xrow[col]);
        } else {
          const float cv = tanhf(acc[i][j] + xrow[col]);
          const float u  = p.G[(size_t)row * p.ldg + 512 + col];
          const float h  = p.Hin[(size_t)row * 512 + col];
          p.Cout[(size_t)row * p.ldc + col] = mask ? (u * h + (1.0f - u) * cv) : h;
        }
      }
    } else { // E_XW
      const int cs = p.cidx[row];
      const float* xrow = p.XT + (size_t)cs * p.ldxt;
#pragma unroll
      for (int j = 0; j < 4; ++j) {
        const int col = cbase + j;
        p.Cout[(size_t)row * p.ldc + col] = acc[i][j] + xrow[col];
      }
    }
  }
}

// ---------------------------------------------------------------------------
// Fused persistent word GRU (r5 version, verbatim): block owns R rows, h/rh/u
// in LDS, T steps internal with __syncthreads only.
// Rows: [0,NU) = forward, [NU,2NU) = backward (dir uniform per block).
// ---------------------------------------------------------------------------
template<int R, int NU, int TT, bool CHARMODE>
__global__ __launch_bounds__(256) void gru_fused(
    const float* __restrict__ Whg,   // [512,1024] h-part of gate weights
    const float* __restrict__ Whc,   // [512,512]  h-part of cand weights
    const float* __restrict__ Xg,    // gate x-part table
    const float* __restrict__ Xc,    // cand x-part table
    const int*   __restrict__ lens,  // [NU]
    const int*   __restrict__ seqs,  // CHARMODE: [NU,TT]
    float* __restrict__ Hout)        // [2*NU, 512]
{
  __shared__ float h_s [R][512];
  __shared__ float rh_s[R][512];
  __shared__ float u_s [R][512];
  __shared__ int   seq_s[CHARMODE ? R * TT : 1];
  __shared__ int   xog_s[R];
  __shared__ int   xoc_s[R];
  __shared__ int   msk_s[R];

  const int tid  = threadIdx.x;
  const int row0 = blockIdx.x * R;
  const int us0  = row0 & (NU - 1);
  const bool bw  = row0 >= NU;

  for (int i = tid; i < R * 512; i += 256) h_s[i >> 9][i & 511] = 0.0f;
  if constexpr (CHARMODE) {
    for (int i = tid; i < R * TT; i += 256)
      seq_s[i] = seqs[(size_t)(us0 + i / TT) * TT + (i % TT)];
  }
  int mylen = 0;
  if (tid < R) mylen = lens[us0 + tid];
  __syncthreads();

  const int c0 = tid << 2;  // phase-1 cols (4 of 1024)
  const int c2 = tid << 1;  // phase-2 cols (2 of 512)

  for (int t = 0; t < TT; ++t) {
    if (tid < R) {
      int pos = bw ? (mylen - 1 - t) : t;
      pos = pos < 0 ? 0 : (pos > TT - 1 ? TT - 1 : pos);
      int xr;
      if constexpr (CHARMODE) xr = seq_s[tid * TT + pos];
      else                    xr = (us0 + tid) * TT + pos;
      xog_s[tid] = xr * 1024;
      xoc_s[tid] = xr * 512;
      msk_s[tid] = (t < mylen) ? 1 : 0;
    }
    __syncthreads();

    // ---- phase 1: gates = sigmoid(h @ Whg + Xg) ; rh / u -> LDS ----
    float4 acc[R];
#pragma unroll
    for (int r = 0; r < R; ++r) acc[r] = make_float4(0.f, 0.f, 0.f, 0.f);
#pragma unroll 8
    for (int k = 0; k < 512; ++k) {
      const float4 w = *reinterpret_cast<const float4*>(Whg + (size_t)k * 1024 + c0);
#pragma unroll
      for (int r = 0; r < R; ++r) {
        const float hv = h_s[r][k];
        acc[r].x += hv * w.x; acc[r].y += hv * w.y;
        acc[r].z += hv * w.z; acc[r].w += hv * w.w;
      }
    }
#pragma unroll
    for (int r = 0; r < R; ++r) {
      const float4 x = *reinterpret_cast<const float4*>(Xg + xog_s[r] + c0);
      float4 g;
      g.x = sigmoidf_(acc[r].x + x.x);
      g.y = sigmoidf_(acc[r].y + x.y);
      g.z = sigmoidf_(acc[r].z + x.z);
      g.w = sigmoidf_(acc[r].w + x.w);
      if (c0 < 512) {        // r-gate cols -> rh = r * h
        const float4 hh = *reinterpret_cast<const float4*>(&h_s[r][c0]);
        rh_s[r][c0 + 0] = g.x * hh.x;
        rh_s[r][c0 + 1] = g.y * hh.y;
        rh_s[r][c0 + 2] = g.z * hh.z;
        rh_s[r][c0 + 3] = g.w * hh.w;
      } else {               // u-gate cols
        u_s[r][c0 - 512 + 0] = g.x;
        u_s[r][c0 - 512 + 1] = g.y;
        u_s[r][c0 - 512 + 2] = g.z;
        u_s[r][c0 - 512 + 3] = g.w;
      }
    }
    __syncthreads();

    // ---- phase 2: c = tanh(rh @ Whc + Xc) ; h' = mask? u*h+(1-u)*c : h ----
    float2 acc2[R];
#pragma unroll
    for (int r = 0; r < R; ++r) acc2[r] = make_float2(0.f, 0.f);
#pragma unroll 8
    for (int k = 0; k < 512; ++k) {
      const float2 w = *reinterpret_cast<const float2*>(Whc + (size_t)k * 512 + c2);
#pragma unroll
      for (int r = 0; r < R; ++r) {
        const float rv = rh_s[r][k];
        acc2[r].x += rv * w.x; acc2[r].y += rv * w.y;
      }
    }
#pragma unroll
    for (int r = 0; r < R; ++r) {
      const float2 x = *reinterpret_cast<const float2*>(Xc + xoc_s[r] + c2);
      const float cx = tanhf(acc2[r].x + x.x);
      const float cy = tanhf(acc2[r].y + x.y);
      if (msk_s[r]) {
        const float ux = u_s[r][c2], uy = u_s[r][c2 + 1];
        const float hx = h_s[r][c2], hy = h_s[r][c2 + 1];
        h_s[r][c2]     = ux * hx + (1.0f - ux) * cx;
        h_s[r][c2 + 1] = uy * hy + (1.0f - uy) * cy;
      }
    }
    __syncthreads();
  }

  for (int i = tid; i < R * 512; i += 256)
    Hout[(size_t)(row0 + (i >> 9)) * 512 + (i & 511)] = h_s[i >> 9][i & 511];
}

// FC head: states = concat(fw,bw) [256,1024] -> leaky_relu(@W1+b1,0.2) -> @W2+b2
__global__ __launch_bounds__(64) void head_k(const float* __restrict__ Hw,
                                             const float* __restrict__ W1,
                                             const float* __restrict__ b1,
                                             const float* __restrict__ W2,
                                             const float* __restrict__ b2,
                                             float* __restrict__ out) {
  __shared__ float s[1024];
  __shared__ float hid[64];
  const int b = blockIdx.x;
  const int tid = threadIdx.x;
  for (int k = tid; k < 512; k += 64) {
    s[k]       = Hw[(size_t)b * 512 + k];
    s[512 + k] = Hw[(size_t)(256 + b) * 512 + k];
  }
  __syncthreads();
  float acc = b1[tid];
  for (int k = 0; k < 1024; ++k) acc += s[k] * W1[k * 64 + tid];
  acc = acc > 0.0f ? acc : 0.2f * acc;  // leaky_relu alpha=0.2
  hid[tid] = acc;
  __syncthreads();
  if (tid < 2) {
    float a = b2[tid];
    for (int k = 0; k < 64; ++k) a += hid[k] * W2[k * 2 + tid];
    out[b * 2 + tid] = a;
  }
}

extern "C" void kernel_launch(void* const* d_in, const int* in_sizes, int n_in,
                              void* d_out, int out_size, void* d_ws, size_t ws_size,
                              hipStream_t stream) {
  const int*   charseqs      = (const int*)d_in[0];
  const int*   charseq_lens  = (const int*)d_in[1];
  const int*   charseq_ids   = (const int*)d_in[2];
  const int*   word_ids      = (const int*)d_in[3];
  const int*   sentence_lens = (const int*)d_in[4];
  const float* char_emb      = (const float*)d_in[5];
  const float* word_emb      = (const float*)d_in[6];
  const float* Wg_c          = (const float*)d_in[7];
  const float* bg_c          = (const float*)d_in[8];
  const float* Wc_c          = (const float*)d_in[9];
  const float* bc_c          = (const float*)d_in[10];
  const float* Wg_w          = (const float*)d_in[11];
  const float* bg_w          = (const float*)d_in[12];
  const float* Wc_w          = (const float*)d_in[13];
  const float* bc_w          = (const float*)d_in[14];
  const float* W1            = (const float*)d_in[15];
  const float* b1            = (const float*)d_in[16];
  const float* W2            = (const float*)d_in[17];
  const float* b2            = (const float*)d_in[18];
  float* out = (float*)d_out;

  float* ws = (float*)d_ws;
  size_t off = 0;
  auto alloc = [&](size_t n) { float* p = ws + off; off += n; return p; };
  float* XTABg = alloc(256 * 1024);           // char gate x-part (+bg_c)
  float* XTABc = alloc(256 * 512);            // char cand x-part (+bc_c)
  float* HcA   = alloc((size_t)4096 * 512);   // char GRU state ping
  float* HcB   = alloc((size_t)4096 * 512);   // char GRU state pong
  float* Gc    = alloc((size_t)4096 * 1024);  // char gates [r|u]
  float* CTABg = alloc((size_t)2048 * 1024);  // per-wordform gate x-part (+bg_w)
  float* CTABc = alloc((size_t)2048 * 512);
  float* XWg   = alloc((size_t)16384 * 1024); // per-(b,t) word gate x-part
  float* XWc   = alloc((size_t)16384 * 512);
  float* Hw    = alloc(512 * 512);            // word bi-GRU final states

  hipMemsetAsync(HcA, 0, (size_t)4096 * 512 * sizeof(float), stream);

  // --- Stage A: char x-part tables  [256,128]@[128,1536] ---
  {
    GemmArgs a{}; a.M = 256; a.N = 1024; a.K = 128;
    a.A = char_emb; a.lda = 128; a.B = Wg_c; a.bias = bg_c; a.Cout = XTABg; a.ldc = 1024;
    gemm_k<A_PLAIN, E_BIAS><<<dim3(1024 / TILE, 256 / TILE), 256, 0, stream>>>(a);
    GemmArgs c{}; c.M = 256; c.N = 512; c.K = 128;
    c.A = char_emb; c.lda = 128; c.B = Wc_c; c.bias = bc_c; c.Cout = XTABc; c.ldc = 512;
    gemm_k<A_PLAIN, E_BIAS><<<dim3(512 / TILE, 256 / TILE), 256, 0, stream>>>(c);
  }

  // --- Stage B: char bi-GRU as GEMM loop, 16 steps, batch 4096 ---
  float* hcur = HcA; float* hnext = HcB;
  for (int t = 0; t < 16; ++t) {
    GemmArgs g{}; g.M = 4096; g.N = 1024; g.K = 512;
    g.A = hcur; g.lda = 512; g.B = Wg_c + 128 * 1024;
    g.XT = XTABg; g.ldxt = 1024; g.seqs = charseqs; g.lens = charseq_lens; g.t = t; g.T = 16;
    g.Cout = Gc; g.ldc = 1024;
    gemm_k<A_PLAIN, E_GATE_CHAR><<<dim3(1024 / TILE, 4096 / TILE), 256, 0, stream>>>(g);

    GemmArgs c{}; c.M = 4096; c.N = 512; c.K = 512;
    c.A = hcur; c.lda = 512; c.G = Gc; c.ldg = 1024; c.B = Wc_c + 128 * 512;
    c.XT = XTABc; c.ldxt = 512; c.seqs = charseqs; c.lens = charseq_lens; c.t = t; c.T = 16;
    c.Hin = hcur; c.Cout = hnext; c.ldc = 512;
    gemm_k<A_RH, E_CAND_CHAR><<<dim3(512 / TILE, 4096 / TILE), 256, 0, stream>>>(c);

    float* tmp = hcur; hcur = hnext; hnext = tmp;
  }
  // after 16 steps hcur == HcA

  // --- Stage C: per-wordform x-part of word GRU  [2048,1024]@[1024,1536] ---
  {
    GemmArgs a{}; a.M = 2048; a.N = 1024; a.K = 1024;
    a.A = hcur; a.B = Wg_w; a.bias = bg_w; a.Cout = CTABg; a.ldc = 1024;
    gemm_k<A_CHARSTATE, E_BIAS><<<dim3(1024 / TILE, 2048 / TILE), 256, 0, stream>>>(a);
    GemmArgs c{}; c.M = 2048; c.N = 512; c.K = 1024;
    c.A = hcur; c.B = Wc_w; c.bias = bc_w; c.Cout = CTABc; c.ldc = 512;
    gemm_k<A_CHARSTATE, E_BIAS><<<dim3(512 / TILE, 2048 / TILE), 256, 0, stream>>>(c);
  }

  // --- Stage D: word-emb x-part + CTAB gather  [16384,256]@[256,1536] ---
  {
    GemmArgs a{}; a.M = 16384; a.N = 1024; a.K = 256;
    a.A = word_emb; a.lda = 256; a.arows = word_ids; a.B = Wg_w + (size_t)1024 * 1024;
    a.XT = CTABg; a.ldxt = 1024; a.cidx = charseq_ids; a.Cout = XWg; a.ldc = 1024;
    gemm_k<A_GATHER, E_XW><<<dim3(1024 / TILE, 16384 / TILE), 256, 0, stream>>>(a);
    GemmArgs c{}; c.M = 16384; c.N = 512; c.K = 256;
    c.A = word_emb; c.lda = 256; c.arows = word_ids; c.B = Wc_w + (size_t)1024 * 512;
    c.XT = CTABc; c.ldxt = 512; c.cidx = charseq_ids; c.Cout = XWc; c.ldc = 512;
    gemm_k<A_GATHER, E_XW><<<dim3(512 / TILE, 16384 / TILE), 256, 0, stream>>>(c);
  }

  // --- Stage E: fused word bi-GRU (512 rows, 64 steps, R=2 -> 256 blocks) ---
  gru_fused<2, 256, 64, false><<<256, 256, 0, stream>>>(
      Wg_w + (size_t)1280 * 1024, Wc_w + (size_t)1280 * 512, XWg, XWc,
      sentence_lens, nullptr, Hw);

  // --- Stage F: FC head ---
  head_k<<<256, 64, 0, stream>>>(Hw, W1, b1, W2, b2, out);
}